// Round 5
// baseline (1758.888 us; speedup 1.0000x reference)
//
#include <hip/hip_runtime.h>
#include <math.h>

// Problem constants
#define B_ 256
#define T_ 2000
#define I_ 80
#define H_ 20
#define G_ 80      // 4*H
#define M_ 512000  // B*T

#define LOG2E 1.442695041f

typedef __attribute__((ext_vector_type(2))) float f32x2;
typedef __attribute__((ext_vector_type(2))) unsigned u32x2;

__device__ __forceinline__ f32x2 mk2(float a, float b) { f32x2 r; r.x = a; r.y = b; return r; }

// Cross-half value swap: returns, in lanes 0-31, the value held by lane+32.
__device__ __forceinline__ float swap_half(float x, int swapidx) {
#if __has_builtin(__builtin_amdgcn_permlane32_swap)
    u32x2 r = __builtin_amdgcn_permlane32_swap(__float_as_uint(x), __float_as_uint(x), false, false);
    return __uint_as_float(r.y);   // lanes<32: other half's value
#else
    return __uint_as_float((unsigned)__builtin_amdgcn_ds_bpermute(swapidx, (int)__float_as_uint(x)));
#endif
}

// ---------------------------------------------------------------------------
// GEMM (layer 0, row-major A): XG[row][d*80 + j*4 + g] =
//   pS_g * (sum_k X[row][k]*Wih[d][k][g*20+j] + B[d][g*20+j])
// ---------------------------------------------------------------------------
template<int K>
__global__ __launch_bounds__(256) void gemm_xg(
    const float* __restrict__ X,     // (M, K) row-major
    const float* __restrict__ Wih,   // (2, K, 80)
    const float* __restrict__ Bias,  // (2, 80)
    float* __restrict__ XG,          // (M, 160) permuted+scaled cols
    int M)
{
    constexpr int KC = 40;
    __shared__ float ws[KC][164];
    __shared__ float xs[KC][100];
    __shared__ float bs[160];

    const int tid  = threadIdx.x;
    const int row0 = blockIdx.x * 96;
    const int tx = tid % 20;
    const int ty = tid / 20;
    const bool run = (ty < 12);

    if (tid < 160) {
        int dd = (tid >= 80);
        int r = tid - 80 * dd;
        int j = r >> 2, g = r & 3;
        float sc = (g == 2) ? 2.0f * LOG2E : -LOG2E;
        bs[tid] = sc * Bias[dd * 80 + g * 20 + j];
    }

    int nrows = M - row0; if (nrows > 96) nrows = 96;

    float acc[8][8];
    bool first = true;

    for (int kc = 0; kc < K; kc += KC) {
        for (int idx = tid; idx < KC * 160; idx += 256) {
            int i = idx / 160, cc = idx - 160 * i;
            int dd = (cc >= 80), r = cc - 80 * dd;
            int j = r >> 2, g = r & 3;
            float sc = (g == 2) ? 2.0f * LOG2E : -LOG2E;
            ws[i][cc] = sc * Wih[(dd * K + kc + i) * 80 + g * 20 + j];
        }
        for (int i4 = tid; i4 < (96 * KC) / 4; i4 += 256) {
            int r = i4 / 10;
            int kk = (i4 - 10 * r) * 4;
            float4 v = make_float4(0.f, 0.f, 0.f, 0.f);
            if (r < nrows)
                v = *(const float4*)(X + (long long)(row0 + r) * K + kc + kk);
            xs[kk][r] = v.x; xs[kk + 1][r] = v.y; xs[kk + 2][r] = v.z; xs[kk + 3][r] = v.w;
        }
        __syncthreads();

        if (first) {
            first = false;
            float bv[8];
            #pragma unroll
            for (int cc = 0; cc < 8; ++cc) bv[cc] = bs[tx * 8 + cc];
            #pragma unroll
            for (int r = 0; r < 8; ++r)
                #pragma unroll
                for (int cc = 0; cc < 8; ++cc) acc[r][cc] = bv[cc];
        }

        if (run) {
            #pragma unroll 4
            for (int k = 0; k < KC; ++k) {
                float a[8], bb[8];
                *(float4*)&a[0]  = *(const float4*)&xs[k][ty * 8];
                *(float4*)&a[4]  = *(const float4*)&xs[k][ty * 8 + 4];
                *(float4*)&bb[0] = *(const float4*)&ws[k][tx * 8];
                *(float4*)&bb[4] = *(const float4*)&ws[k][tx * 8 + 4];
                #pragma unroll
                for (int r = 0; r < 8; ++r)
                    #pragma unroll
                    for (int cc = 0; cc < 8; ++cc)
                        acc[r][cc] = fmaf(a[r], bb[cc], acc[r][cc]);
            }
        }
        __syncthreads();
    }

    if (run) {
        #pragma unroll
        for (int r = 0; r < 8; ++r) {
            int row = row0 + ty * 8 + r;
            if (row < M) {
                float* dst = XG + (long long)row * 160 + tx * 8;
                *(float4*)(dst)     = *(float4*)&acc[r][0];
                *(float4*)(dst + 4) = *(float4*)&acc[r][4];
            }
        }
    }
}

// ---------------------------------------------------------------------------
// GEMM (layer 1, TRANSPOSED A): A[row=(b,t)][k] = H0t[(b*40+k)*T + t]
// ---------------------------------------------------------------------------
__global__ __launch_bounds__(256) void gemm_xg_tA(
    const float* __restrict__ H0t,   // (B, 40, T)
    const float* __restrict__ Wih,   // (2, 40, 80)
    const float* __restrict__ Bias,  // (2, 80)
    float* __restrict__ XG,          // (M, 160) permuted+scaled cols
    int T)
{
    constexpr int K = 40;
    __shared__ float ws[K][164];
    __shared__ float xs[K][100];
    __shared__ float bs[160];

    const int tid = threadIdx.x;
    const int bb  = blockIdx.x / 21;
    const int tc  = blockIdx.x % 21;
    const int t0  = tc * 96;
    const int tx  = tid % 20;
    const int ty  = tid / 20;
    const bool run = (ty < 12);

    if (tid < 160) {
        int dd = (tid >= 80);
        int r = tid - 80 * dd;
        int j = r >> 2, g = r & 3;
        float sc = (g == 2) ? 2.0f * LOG2E : -LOG2E;
        bs[tid] = sc * Bias[dd * 80 + g * 20 + j];
    }

    int nrows = T - t0; if (nrows > 96) nrows = 96;   // 96 or 80 (both %4==0)

    // stage weights (single K-chunk)
    for (int idx = tid; idx < K * 160; idx += 256) {
        int i = idx / 160, cc = idx - 160 * i;
        int dd = (cc >= 80), r = cc - 80 * dd;
        int j = r >> 2, g = r & 3;
        float sc = (g == 2) ? 2.0f * LOG2E : -LOG2E;
        ws[i][cc] = sc * Wih[(dd * K + i) * 80 + g * 20 + j];
    }
    // stage A^T: xs[k][r] = H0t[(bb*40+k)*T + t0 + r], float4 along r(=t)
    for (int i4 = tid; i4 < K * 24; i4 += 256) {
        int k = i4 / 24;
        int r = (i4 - 24 * k) * 4;
        float4 v = make_float4(0.f, 0.f, 0.f, 0.f);
        if (r < nrows)
            v = *(const float4*)(H0t + ((long long)bb * 40 + k) * T + t0 + r);
        *(float4*)&xs[k][r] = v;
    }
    __syncthreads();

    float acc[8][8];
    {
        float bv[8];
        #pragma unroll
        for (int cc = 0; cc < 8; ++cc) bv[cc] = bs[tx * 8 + cc];
        #pragma unroll
        for (int r = 0; r < 8; ++r)
            #pragma unroll
            for (int cc = 0; cc < 8; ++cc) acc[r][cc] = bv[cc];
    }

    if (run) {
        #pragma unroll 4
        for (int k = 0; k < K; ++k) {
            float a[8], bb2[8];
            *(float4*)&a[0]   = *(const float4*)&xs[k][ty * 8];
            *(float4*)&a[4]   = *(const float4*)&xs[k][ty * 8 + 4];
            *(float4*)&bb2[0] = *(const float4*)&ws[k][tx * 8];
            *(float4*)&bb2[4] = *(const float4*)&ws[k][tx * 8 + 4];
            #pragma unroll
            for (int r = 0; r < 8; ++r)
                #pragma unroll
                for (int cc = 0; cc < 8; ++cc)
                    acc[r][cc] = fmaf(a[r], bb2[cc], acc[r][cc]);
        }

        #pragma unroll
        for (int r = 0; r < 8; ++r) {
            int rr = ty * 8 + r;
            if (rr < nrows) {
                long long row = (long long)bb * T + t0 + rr;
                float* dst = XG + row * 160 + tx * 8;
                *(float4*)(dst)     = *(float4*)&acc[r][0];
                *(float4*)(dst + 4) = *(float4*)&acc[r][4];
            }
        }
    }
}

// ---------------------------------------------------------------------------
// LSTM scan v11: TWO SEQUENCES PER WAVE (fwd+bwd of one batch), gate-split.
//
// v10 measured ~487cy/step: ~210cy issue + ~280cy EXPOSED dependency latency
// (matvec->reduce->exp2->rcp->swap->c->tanh->readlane, all serial). One
// sequence per wave cannot hide that chain. v11 fuses the fwd and bwd
// recurrences of one batch into the same wave (independent chains): while F
// waits on its transcendentals, R issues FMAs, and vice versa. Issue per
// step-pair ~2x210cy, stalls mutually hidden -> ~230-280cy/step.
// Per-sequence instruction stream and accumulation order identical to v10
// -> bit-identical output. Grid = B (256 waves, 1/CU).
// ---------------------------------------------------------------------------
__attribute__((amdgpu_waves_per_eu(1, 1)))
__global__ __launch_bounds__(64) void lstm_scan(
    const float* __restrict__ xg,    // (B,T,2,20,4) scaled, unit-major
    const float* __restrict__ w_hh,  // (2, 20, 80) natural (k, g*20+j)
    float* __restrict__ h_out,       // (B, 40, T): [(b*40 + d*20 + j)*T + t]
    int T)
{
    const int b    = blockIdx.x;          // 0..255
    const int lane = threadIdx.x & 63;
    const int half = lane >> 5;           // 0: gates i,f   1: gates g,o
    const int j    = lane & 31;
    const bool act_lane = (lane < H_);    // lanes 0..19 hold h / store
    const int jj   = (j < H_) ? j : 0;

    const int swapidx = ((lane + 32) & 63) << 2;   // bpermute fallback index

    // Per-lane gates: A = (half? g : i), B = (half? o : f)
    const int gA = half ? 2 : 0;
    const int gB = gA + 1;
    const float scA = half ? (2.0f * LOG2E) : (-LOG2E);
    const float scB = -LOG2E;

    // Pre-scaled packed recurrent weights for BOTH directions.
    f32x2 wAF[10], wBF[10], wAR[10], wBR[10];
    {
        const float* wbF = w_hh;               // d=0 (fwd)
        const float* wbR = w_hh + H_ * G_;     // d=1 (bwd)
        #pragma unroll
        for (int i = 0; i < 10; ++i) {
            wAF[i] = mk2(scA * wbF[(2 * i) * G_ + gA * 20 + jj],
                         scA * wbF[(2 * i + 1) * G_ + gA * 20 + jj]);
            wBF[i] = mk2(scB * wbF[(2 * i) * G_ + gB * 20 + jj],
                         scB * wbF[(2 * i + 1) * G_ + gB * 20 + jj]);
            wAR[i] = mk2(scA * wbR[(2 * i) * G_ + gA * 20 + jj],
                         scA * wbR[(2 * i + 1) * G_ + gA * 20 + jj]);
            wBR[i] = mk2(scB * wbR[(2 * i) * G_ + gB * 20 + jj],
                         scB * wbR[(2 * i + 1) * G_ + gB * 20 + jj]);
        }
    }

    // Wave-uniform h (SGPRs via readlane), one set per direction
    float shF[20], shR[20];
    #pragma unroll
    for (int k = 0; k < 20; ++k) { shF[k] = 0.f; shR[k] = 0.f; }
    float cF = 0.f, cR = 0.f;

    // F: t = 0..T-1 ascending; R: t = T-1..0 descending
    const float* pfF = xg + ((long long)(b * T) * 2 + 0) * 80 + 4 * jj + 2 * half;
    const float* pfR = xg + ((long long)(b * T + T - 1) * 2 + 1) * 80 + 4 * jj + 2 * half;

    // transposed h store pointers: groups of 4 t's, 16B aligned (low lanes store)
    float* hpF = h_out + ((long long)b * 40 + jj) * T;
    float* hpR = h_out + ((long long)b * 40 + 20 + jj) * T + (T - 4);

    constexpr int PF = 8;
    f32x2 pxF[PF], pxR[PF];
    #pragma unroll
    for (int s = 0; s < PF; ++s) {
        pxF[s] = *(const f32x2*)pfF; pfF += 160;
        pxR[s] = *(const f32x2*)pfR; pfR -= 160;
    }

    float hqF0 = 0.f, hqF1 = 0.f, hqF2 = 0.f, hqF3 = 0.f;
    float hqR0 = 0.f, hqR1 = 0.f, hqR2 = 0.f, hqR3 = 0.f;

    for (int tb = 0; tb < T; tb += PF) {
        #pragma unroll
        for (int s = 0; s < PF; ++s) {
            const f32x2 vF = pxF[s];
            pxF[s] = *(const f32x2*)pfF; pfF += 160;   // prefetch t+PF
            const f32x2 vR = pxR[s];
            pxR[s] = *(const f32x2*)pfR; pfR -= 160;

            // 8 pk-chains: {F,R} x 2 gates x 2 k-halves, depth 5 each
            f32x2 aA1F = mk2(vF.x, 0.f), aA2F = mk2(0.f, 0.f);
            f32x2 aB1F = mk2(vF.y, 0.f), aB2F = mk2(0.f, 0.f);
            f32x2 aA1R = mk2(vR.x, 0.f), aA2R = mk2(0.f, 0.f);
            f32x2 aB1R = mk2(vR.y, 0.f), aB2R = mk2(0.f, 0.f);
            #pragma unroll
            for (int i = 0; i < 5; ++i) {
                const f32x2 hloF = mk2(shF[2 * i],      shF[2 * i + 1]);
                const f32x2 hhiF = mk2(shF[10 + 2 * i], shF[11 + 2 * i]);
                const f32x2 hloR = mk2(shR[2 * i],      shR[2 * i + 1]);
                const f32x2 hhiR = mk2(shR[10 + 2 * i], shR[11 + 2 * i]);
                aA1F = __builtin_elementwise_fma(wAF[i],     hloF, aA1F);
                aA1R = __builtin_elementwise_fma(wAR[i],     hloR, aA1R);
                aA2F = __builtin_elementwise_fma(wAF[i + 5], hhiF, aA2F);
                aA2R = __builtin_elementwise_fma(wAR[i + 5], hhiR, aA2R);
                aB1F = __builtin_elementwise_fma(wBF[i],     hloF, aB1F);
                aB1R = __builtin_elementwise_fma(wBR[i],     hloR, aB1R);
                aB2F = __builtin_elementwise_fma(wBF[i + 5], hhiF, aB2F);
                aB2R = __builtin_elementwise_fma(wBR[i + 5], hhiR, aB2R);
            }
            const f32x2 tAF = aA1F + aA2F;
            const f32x2 tBF = aB1F + aB2F;
            const f32x2 tAR = aA1R + aA2R;
            const f32x2 tBR = aB1R + aB2R;
            const float mAF = tAF.x + tAF.y;   // low: m_i   high: m_g
            const float mBF = tBF.x + tBF.y;   // low: m_f   high: m_o
            const float mAR = tAR.x + tAR.y;
            const float mBR = tBR.x + tBR.y;

            // shared sigma-core per sequence
            const float sAF = __builtin_amdgcn_rcpf(1.0f + __builtin_amdgcn_exp2f(mAF));
            const float sBF = __builtin_amdgcn_rcpf(1.0f + __builtin_amdgcn_exp2f(mBF));
            const float sAR = __builtin_amdgcn_rcpf(1.0f + __builtin_amdgcn_exp2f(mAR));
            const float sBR = __builtin_amdgcn_rcpf(1.0f + __builtin_amdgcn_exp2f(mBR));

            // bring high half's values to the low half
            const float sAxF = swap_half(sAF, swapidx);  // low: sig(m_g)
            const float goxF = swap_half(sBF, swapidx);  // low: go
            const float sAxR = swap_half(sAR, swapidx);
            const float goxR = swap_half(sBR, swapidx);

            const float ggF = fmaf(-2.0f, sAxF, 1.0f);
            const float ggR = fmaf(-2.0f, sAxR, 1.0f);
            cF = fmaf(sBF, cF, sAF * ggF);
            cR = fmaf(sBR, cR, sAR * ggR);
            const float thF = fmaf(-2.0f,
                __builtin_amdgcn_rcpf(1.0f + __builtin_amdgcn_exp2f(2.0f * LOG2E * cF)), 1.0f);
            const float thR = fmaf(-2.0f,
                __builtin_amdgcn_rcpf(1.0f + __builtin_amdgcn_exp2f(2.0f * LOG2E * cR)), 1.0f);
            const float hjF = goxF * thF;      // valid in lanes 0..19
            const float hjR = goxR * thR;

            // buffer h (phase = s&3); one float4 store per 4 steps per seq
            {
                const int p = s & 3;
                if (p == 0) { hqF0 = hjF; hqR0 = hjR; }
                else if (p == 1) { hqF1 = hjF; hqR1 = hjR; }
                else if (p == 2) { hqF2 = hjF; hqR2 = hjR; }
                else {
                    hqF3 = hjF; hqR3 = hjR;
                    float4 svF, svR;
                    svF.x = hqF0; svF.y = hqF1; svF.z = hqF2; svF.w = hqF3;
                    svR.x = hqR3; svR.y = hqR2; svR.z = hqR1; svR.w = hqR0;  // reversed
                    if (act_lane) {
                        *(float4*)hpF = svF;
                        *(float4*)hpR = svR;
                    }
                    hpF += 4;
                    hpR -= 4;
                }
            }

            // broadcast h (lanes 0..19) into wave-uniform SGPR copies
            #pragma unroll
            for (int k = 0; k < 20; ++k) {
                shF[k] = __uint_as_float(__builtin_amdgcn_readlane(__float_as_uint(hjF), k));
                shR[k] = __uint_as_float(__builtin_amdgcn_readlane(__float_as_uint(hjR), k));
            }
        }
    }
}

// ---------------------------------------------------------------------------
// FC over transposed h: out[b*T+t] = sum_u H1t[(b*40+u)*T+t]*w[u] + bias.
// ---------------------------------------------------------------------------
__global__ __launch_bounds__(256) void fc_t(
    const float* __restrict__ H1t,  // (B, 40, T)
    const float* __restrict__ Wf,   // (40,)
    const float* __restrict__ Bf,   // (1,)
    float* __restrict__ Out,        // (B, T)
    int T)
{
    const int b   = blockIdx.x;
    const int t   = blockIdx.y * 1024 + threadIdx.x * 4;
    if (t > T - 4) return;

    const float bias = Bf[0];
    float4 acc = make_float4(bias, bias, bias, bias);
    const float* base = H1t + (long long)b * 40 * T + t;
    #pragma unroll 8
    for (int u = 0; u < 40; ++u) {
        const float wv = Wf[u];
        const float4 hv = *(const float4*)(base + (long long)u * T);
        acc.x = fmaf(hv.x, wv, acc.x);
        acc.y = fmaf(hv.y, wv, acc.y);
        acc.z = fmaf(hv.z, wv, acc.z);
        acc.w = fmaf(hv.w, wv, acc.w);
    }
    *(float4*)(Out + (long long)b * T + t) = acc;
}

// ---------------------------------------------------------------------------
extern "C" void kernel_launch(void* const* d_in, const int* in_sizes, int n_in,
                              void* d_out, int out_size, void* d_ws, size_t ws_size,
                              hipStream_t stream) {
    const float* x     = (const float*)d_in[0];
    const float* wih0  = (const float*)d_in[1];
    const float* whh0  = (const float*)d_in[2];
    const float* b0    = (const float*)d_in[3];
    const float* wih1  = (const float*)d_in[4];
    const float* whh1  = (const float*)d_in[5];
    const float* b1    = (const float*)d_in[6];
    const float* fcw   = (const float*)d_in[7];
    const float* fcb   = (const float*)d_in[8];
    float* out = (float*)d_out;

    // Workspace (floats): 2048-float pads around xg for the scan's
    // unconditional ±8-step prefetch.
    float* ws = (float*)d_ws;
    float* xg  = ws + 2048;                  // B*T*2*80 = 81,920,000 floats
    float* h0t = xg + 81920000LL + 2048;     // B*40*T   = 20,480,000 floats
    float* h1t = h0t + 20480000LL;           // B*40*T   = 20,480,000 floats

    const int M = M_;
    const int gemm_grid = (M + 95) / 96;     // 5334

    // Layer 0 (row-major A)
    gemm_xg<80><<<dim3(gemm_grid), dim3(256), 0, stream>>>(x, wih0, b0, xg, M);
    lstm_scan<<<dim3(B_), dim3(64), 0, stream>>>(xg, whh0, h0t, T_);
    // Layer 1 (transposed A)
    gemm_xg_tA<<<dim3(B_ * 21), dim3(256), 0, stream>>>(h0t, wih1, b1, xg, T_);
    lstm_scan<<<dim3(B_), dim3(64), 0, stream>>>(xg, whh1, h1t, T_);
    // FC (transposed input, coalesced)
    fc_t<<<dim3(B_, 2), dim3(256), 0, stream>>>(h1t, fcw, fcb, out, T_);
}

// Round 6
// 1334.195 us; speedup vs baseline: 1.3183x; 1.3183x over previous
//
#include <hip/hip_runtime.h>
#include <math.h>

// Problem constants
#define B_ 256
#define T_ 2000
#define I_ 80
#define H_ 20
#define G_ 80      // 4*H
#define M_ 512000  // B*T

#define LOG2E 1.442695041f

typedef __attribute__((ext_vector_type(2))) float f32x2;
typedef __attribute__((ext_vector_type(2))) unsigned u32x2;

__device__ __forceinline__ f32x2 mk2(float a, float b) { f32x2 r; r.x = a; r.y = b; return r; }

// Cross-half value swap: returns, in lanes 0-31, the value held by lane+32.
__device__ __forceinline__ float swap_half(float x, int swapidx) {
#if __has_builtin(__builtin_amdgcn_permlane32_swap)
    u32x2 r = __builtin_amdgcn_permlane32_swap(__float_as_uint(x), __float_as_uint(x), false, false);
    return __uint_as_float(r.y);   // lanes<32: other half's value
#else
    return __uint_as_float((unsigned)__builtin_amdgcn_ds_bpermute(swapidx, (int)__float_as_uint(x)));
#endif
}

// B-fragment LDS layout (both GEMMs): chunk-major with stride 332 floats.
//   ws2[ct*332 + k*8 + w]  holds scaled W[k][ct*8+w],  ct = col/8 (0..19)
// Read addr = tx*332 + k*8: 12*tx mod 32 cycles through 8 DISJOINT 4-bank
// spans -> max 3-way conflict (was 5-way with row-major [k][164]).
#define WS2_STRIDE 332
#define WS2_SIZE   6640   // 19*332 + 320, rounded up

// ---------------------------------------------------------------------------
// GEMM (layer 0, row-major A): XG[row][d*80 + j*4 + g] =
//   pS_g * (sum_k X[row][k]*Wih[d][k][g*20+j] + B[d][g*20+j])
// Inner loop: packed f32x2 FMAs (halves VALU issue), swizzled B layout.
// ---------------------------------------------------------------------------
template<int K>
__global__ __launch_bounds__(256) void gemm_xg(
    const float* __restrict__ X,     // (M, K) row-major
    const float* __restrict__ Wih,   // (2, K, 80)
    const float* __restrict__ Bias,  // (2, 80)
    float* __restrict__ XG,          // (M, 160) permuted+scaled cols
    int M)
{
    constexpr int KC = 40;
    __shared__ float ws2[WS2_SIZE];
    __shared__ float xs[KC][100];
    __shared__ float bs[160];

    const int tid  = threadIdx.x;
    const int row0 = blockIdx.x * 96;
    const int tx = tid % 20;
    const int ty = tid / 20;
    const bool run = (ty < 12);

    if (tid < 160) {
        int dd = (tid >= 80);
        int r = tid - 80 * dd;
        int j = r >> 2, g = r & 3;
        float sc = (g == 2) ? 2.0f * LOG2E : -LOG2E;
        bs[tid] = sc * Bias[dd * 80 + g * 20 + j];
    }

    int nrows = M - row0; if (nrows > 96) nrows = 96;

    f32x2 acc[8][4];
    bool first = true;
    const float* wsp = &ws2[tx * WS2_STRIDE];

    for (int kc = 0; kc < K; kc += KC) {
        for (int idx = tid; idx < KC * 160; idx += 256) {
            int i = idx / 160, cc = idx - 160 * i;
            int dd = (cc >= 80), r = cc - 80 * dd;
            int j = r >> 2, g = r & 3;
            float sc = (g == 2) ? 2.0f * LOG2E : -LOG2E;
            ws2[(cc >> 3) * WS2_STRIDE + i * 8 + (cc & 7)] =
                sc * Wih[(dd * K + kc + i) * 80 + g * 20 + j];
        }
        for (int i4 = tid; i4 < (96 * KC) / 4; i4 += 256) {
            int r = i4 / 10;
            int kk = (i4 - 10 * r) * 4;
            float4 v = make_float4(0.f, 0.f, 0.f, 0.f);
            if (r < nrows)
                v = *(const float4*)(X + (long long)(row0 + r) * K + kc + kk);
            xs[kk][r] = v.x; xs[kk + 1][r] = v.y; xs[kk + 2][r] = v.z; xs[kk + 3][r] = v.w;
        }
        __syncthreads();

        if (first) {
            first = false;
            #pragma unroll
            for (int p = 0; p < 4; ++p) {
                const f32x2 bv = mk2(bs[tx * 8 + 2 * p], bs[tx * 8 + 2 * p + 1]);
                #pragma unroll
                for (int r = 0; r < 8; ++r) acc[r][p] = bv;
            }
        }

        if (run) {
            #pragma unroll 4
            for (int k = 0; k < KC; ++k) {
                float a[8];
                f32x2 b2[4];
                *(float4*)&a[0]  = *(const float4*)&xs[k][ty * 8];
                *(float4*)&a[4]  = *(const float4*)&xs[k][ty * 8 + 4];
                *(float4*)&b2[0] = *(const float4*)&wsp[k * 8];
                *(float4*)&b2[2] = *(const float4*)&wsp[k * 8 + 4];
                #pragma unroll
                for (int r = 0; r < 8; ++r) {
                    const f32x2 av = mk2(a[r], a[r]);
                    #pragma unroll
                    for (int p = 0; p < 4; ++p)
                        acc[r][p] = __builtin_elementwise_fma(av, b2[p], acc[r][p]);
                }
            }
        }
        __syncthreads();
    }

    if (run) {
        #pragma unroll
        for (int r = 0; r < 8; ++r) {
            int row = row0 + ty * 8 + r;
            if (row < M) {
                float* dst = XG + (long long)row * 160 + tx * 8;
                *(float4*)(dst)     = *(float4*)&acc[r][0];
                *(float4*)(dst + 4) = *(float4*)&acc[r][2];
            }
        }
    }
}

// ---------------------------------------------------------------------------
// GEMM (layer 1, TRANSPOSED A): A[row=(b,t)][k] = H0t[(b*40+k)*T + t]
// Same pk-FMA inner loop + swizzled B layout. K=40, single chunk.
// ---------------------------------------------------------------------------
__global__ __launch_bounds__(256) void gemm_xg_tA(
    const float* __restrict__ H0t,   // (B, 40, T)
    const float* __restrict__ Wih,   // (2, 40, 80)
    const float* __restrict__ Bias,  // (2, 80)
    float* __restrict__ XG,          // (M, 160) permuted+scaled cols
    int T)
{
    constexpr int K = 40;
    __shared__ float ws2[WS2_SIZE];
    __shared__ float xs[K][100];
    __shared__ float bs[160];

    const int tid = threadIdx.x;
    const int bb  = blockIdx.x / 21;
    const int tc  = blockIdx.x % 21;
    const int t0  = tc * 96;
    const int tx  = tid % 20;
    const int ty  = tid / 20;
    const bool run = (ty < 12);

    if (tid < 160) {
        int dd = (tid >= 80);
        int r = tid - 80 * dd;
        int j = r >> 2, g = r & 3;
        float sc = (g == 2) ? 2.0f * LOG2E : -LOG2E;
        bs[tid] = sc * Bias[dd * 80 + g * 20 + j];
    }

    int nrows = T - t0; if (nrows > 96) nrows = 96;   // 96 or 80 (both %4==0)

    // stage weights (single K-chunk) into swizzled layout
    for (int idx = tid; idx < K * 160; idx += 256) {
        int i = idx / 160, cc = idx - 160 * i;
        int dd = (cc >= 80), r = cc - 80 * dd;
        int j = r >> 2, g = r & 3;
        float sc = (g == 2) ? 2.0f * LOG2E : -LOG2E;
        ws2[(cc >> 3) * WS2_STRIDE + i * 8 + (cc & 7)] =
            sc * Wih[(dd * K + i) * 80 + g * 20 + j];
    }
    // stage A^T: xs[k][r] = H0t[(bb*40+k)*T + t0 + r], float4 along r(=t)
    for (int i4 = tid; i4 < K * 24; i4 += 256) {
        int k = i4 / 24;
        int r = (i4 - 24 * k) * 4;
        float4 v = make_float4(0.f, 0.f, 0.f, 0.f);
        if (r < nrows)
            v = *(const float4*)(H0t + ((long long)bb * 40 + k) * T + t0 + r);
        *(float4*)&xs[k][r] = v;
    }
    __syncthreads();

    f32x2 acc[8][4];
    #pragma unroll
    for (int p = 0; p < 4; ++p) {
        const f32x2 bv = mk2(bs[tx * 8 + 2 * p], bs[tx * 8 + 2 * p + 1]);
        #pragma unroll
        for (int r = 0; r < 8; ++r) acc[r][p] = bv;
    }

    if (run) {
        const float* wsp = &ws2[tx * WS2_STRIDE];
        #pragma unroll 4
        for (int k = 0; k < K; ++k) {
            float a[8];
            f32x2 b2[4];
            *(float4*)&a[0]  = *(const float4*)&xs[k][ty * 8];
            *(float4*)&a[4]  = *(const float4*)&xs[k][ty * 8 + 4];
            *(float4*)&b2[0] = *(const float4*)&wsp[k * 8];
            *(float4*)&b2[2] = *(const float4*)&wsp[k * 8 + 4];
            #pragma unroll
            for (int r = 0; r < 8; ++r) {
                const f32x2 av = mk2(a[r], a[r]);
                #pragma unroll
                for (int p = 0; p < 4; ++p)
                    acc[r][p] = __builtin_elementwise_fma(av, b2[p], acc[r][p]);
            }
        }

        #pragma unroll
        for (int r = 0; r < 8; ++r) {
            int rr = ty * 8 + r;
            if (rr < nrows) {
                long long row = (long long)bb * T + t0 + rr;
                float* dst = XG + row * 160 + tx * 8;
                *(float4*)(dst)     = *(float4*)&acc[r][0];
                *(float4*)(dst + 4) = *(float4*)&acc[r][2];
            }
        }
    }
}

// ---------------------------------------------------------------------------
// LSTM scan v10 (EXACT revert — measured 406us/scan): gate-split across wave
// halves, one direction per wave, grid = B*2 (2 waves/CU on separate SIMDs).
// v11 (two seqs fused per wave) regressed: fusion's intra-wave overlap (747cy
// per pair) loses to free 2-SIMD parallelism (487cy/step each).
// ---------------------------------------------------------------------------
__attribute__((amdgpu_waves_per_eu(1, 1)))
__global__ __launch_bounds__(64) void lstm_scan(
    const float* __restrict__ xg,    // (B,T,2,20,4) scaled, unit-major
    const float* __restrict__ w_hh,  // (2, 20, 80) natural (k, g*20+j)
    float* __restrict__ h_out,       // (B, 40, T): [(b*40 + d*20 + j)*T + t]
    int T)
{
    const int bd   = blockIdx.x;          // 0..511
    const int b    = bd >> 1;
    const int d    = bd & 1;
    const int lane = threadIdx.x & 63;
    const int half = lane >> 5;           // 0: gates i,f   1: gates g,o
    const int j    = lane & 31;
    const bool act_lane = (lane < H_);    // lanes 0..19 hold h / store
    const int jj   = (j < H_) ? j : 0;
    const bool isB = (d == 1);

    const int swapidx = ((lane + 32) & 63) << 2;   // bpermute fallback index

    // Per-lane gates: A = (half? g : i), B = (half? o : f)
    const int gA = half ? 2 : 0;
    const int gB = gA + 1;
    const float scA = half ? (2.0f * LOG2E) : (-LOG2E);
    const float scB = -LOG2E;

    // Pre-scaled packed recurrent weights; k-pairs i=0..9 cover k=2i,2i+1.
    f32x2 wA[10], wB[10];
    const float* wb = w_hh + d * (H_ * G_);
    #pragma unroll
    for (int i = 0; i < 10; ++i) {
        wA[i] = mk2(scA * wb[(2 * i) * G_ + gA * 20 + jj],
                    scA * wb[(2 * i + 1) * G_ + gA * 20 + jj]);
        wB[i] = mk2(scB * wb[(2 * i) * G_ + gB * 20 + jj],
                    scB * wb[(2 * i + 1) * G_ + gB * 20 + jj]);
    }

    // Wave-uniform h (SGPRs via readlane)
    float sh[20];
    #pragma unroll
    for (int k = 0; k < 20; ++k) sh[k] = 0.f;
    float c = 0.f;

    const int t0    = isB ? (T - 1) : 0;
    const int rstep = isB ? -160 : 160;
    // low half reads gates (0,1) = floats +0..1; high half gates (2,3) = +2..3
    const float* pf = xg + ((long long)(b * T + t0) * 2 + d) * 80 + 4 * jj + 2 * half;

    // transposed h store pointer: group of 4 t's, 16B aligned (low half stores)
    float* hp = h_out + ((long long)b * 40 + d * 20 + jj) * T + (isB ? T - 4 : 0);
    const int hgstep = isB ? -4 : 4;

    constexpr int PF = 8;
    f32x2 px[PF];
    #pragma unroll
    for (int s = 0; s < PF; ++s) { px[s] = *(const f32x2*)pf; pf += rstep; }

    float hq0 = 0.f, hq1 = 0.f, hq2 = 0.f, hq3 = 0.f;

    for (int tb = 0; tb < T; tb += PF) {
        #pragma unroll
        for (int s = 0; s < PF; ++s) {
            const f32x2 v = px[s];
            px[s] = *(const f32x2*)pf; pf += rstep;   // prefetch t+PF

            // 4 pk-chains: 2 gates x 2 k-halves, depth 5 each
            f32x2 aA1 = mk2(v.x, 0.f);
            f32x2 aA2 = mk2(0.f, 0.f);
            f32x2 aB1 = mk2(v.y, 0.f);
            f32x2 aB2 = mk2(0.f, 0.f);
            #pragma unroll
            for (int i = 0; i < 5; ++i) {
                const f32x2 hlo = mk2(sh[2 * i],      sh[2 * i + 1]);
                const f32x2 hhi = mk2(sh[10 + 2 * i], sh[11 + 2 * i]);
                aA1 = __builtin_elementwise_fma(wA[i],     hlo, aA1);
                aA2 = __builtin_elementwise_fma(wA[i + 5], hhi, aA2);
                aB1 = __builtin_elementwise_fma(wB[i],     hlo, aB1);
                aB2 = __builtin_elementwise_fma(wB[i + 5], hhi, aB2);
            }
            const f32x2 tA = aA1 + aA2;
            const f32x2 tB = aB1 + aB2;
            const float mA = tA.x + tA.y;    // low: m_i   high: m_g
            const float mB = tB.x + tB.y;    // low: m_f   high: m_o

            // shared sigma-core (both halves execute the same trans ops)
            const float sA = __builtin_amdgcn_rcpf(1.0f + __builtin_amdgcn_exp2f(mA));
            const float sB = __builtin_amdgcn_rcpf(1.0f + __builtin_amdgcn_exp2f(mB));
            // low lanes: sA = gi, sB = gf.  high lanes: sA = sig(m_g), sB = go.

            // bring high half's values to the low half
            const float sAx = swap_half(sA, swapidx);  // low: sig(m_g) of own unit
            const float gox = swap_half(sB, swapidx);  // low: go of own unit

            const float gg = fmaf(-2.0f, sAx, 1.0f);   // low: tanh(g_raw)
            c = fmaf(sB, c, sA * gg);                  // low: gf*c + gi*gg
            const float th = fmaf(-2.0f,
                __builtin_amdgcn_rcpf(1.0f + __builtin_amdgcn_exp2f(2.0f * LOG2E * c)), 1.0f);
            const float hj = gox * th;                 // valid in lanes 0..19

            // buffer h (phase = s&3); one float4 store per 4 steps (low half)
            {
                const int p = s & 3;
                if (p == 0) hq0 = hj;
                else if (p == 1) hq1 = hj;
                else if (p == 2) hq2 = hj;
                else {
                    hq3 = hj;
                    float4 sv;   // bwd wrote t descending -> reverse for memory order
                    sv.x = isB ? hq3 : hq0;
                    sv.y = isB ? hq2 : hq1;
                    sv.z = isB ? hq1 : hq2;
                    sv.w = isB ? hq0 : hq3;
                    if (act_lane) *(float4*)hp = sv;
                    hp += hgstep;
                }
            }

            // broadcast h (lanes 0..19) into wave-uniform SGPR copies
            #pragma unroll
            for (int k = 0; k < 20; ++k)
                sh[k] = __uint_as_float(__builtin_amdgcn_readlane(__float_as_uint(hj), k));
        }
    }
}

// ---------------------------------------------------------------------------
// FC over transposed h: out[b*T+t] = sum_u H1t[(b*40+u)*T+t]*w[u] + bias.
// ---------------------------------------------------------------------------
__global__ __launch_bounds__(256) void fc_t(
    const float* __restrict__ H1t,  // (B, 40, T)
    const float* __restrict__ Wf,   // (40,)
    const float* __restrict__ Bf,   // (1,)
    float* __restrict__ Out,        // (B, T)
    int T)
{
    const int b   = blockIdx.x;
    const int t   = blockIdx.y * 1024 + threadIdx.x * 4;
    if (t > T - 4) return;

    const float bias = Bf[0];
    float4 acc = make_float4(bias, bias, bias, bias);
    const float* base = H1t + (long long)b * 40 * T + t;
    #pragma unroll 8
    for (int u = 0; u < 40; ++u) {
        const float wv = Wf[u];
        const float4 hv = *(const float4*)(base + (long long)u * T);
        acc.x = fmaf(hv.x, wv, acc.x);
        acc.y = fmaf(hv.y, wv, acc.y);
        acc.z = fmaf(hv.z, wv, acc.z);
        acc.w = fmaf(hv.w, wv, acc.w);
    }
    *(float4*)(Out + (long long)b * T + t) = acc;
}

// ---------------------------------------------------------------------------
extern "C" void kernel_launch(void* const* d_in, const int* in_sizes, int n_in,
                              void* d_out, int out_size, void* d_ws, size_t ws_size,
                              hipStream_t stream) {
    const float* x     = (const float*)d_in[0];
    const float* wih0  = (const float*)d_in[1];
    const float* whh0  = (const float*)d_in[2];
    const float* b0    = (const float*)d_in[3];
    const float* wih1  = (const float*)d_in[4];
    const float* whh1  = (const float*)d_in[5];
    const float* b1    = (const float*)d_in[6];
    const float* fcw   = (const float*)d_in[7];
    const float* fcb   = (const float*)d_in[8];
    float* out = (float*)d_out;

    // Workspace (floats): 2048-float pads around xg for the scan's
    // unconditional ±8-step prefetch.
    float* ws = (float*)d_ws;
    float* xg  = ws + 2048;                  // B*T*2*80 = 81,920,000 floats
    float* h0t = xg + 81920000LL + 2048;     // B*40*T   = 20,480,000 floats
    float* h1t = h0t + 20480000LL;           // B*40*T   = 20,480,000 floats

    const int M = M_;
    const int gemm_grid = (M + 95) / 96;     // 5334

    // Layer 0 (row-major A)
    gemm_xg<80><<<dim3(gemm_grid), dim3(256), 0, stream>>>(x, wih0, b0, xg, M);
    lstm_scan<<<dim3(B_ * 2), dim3(64), 0, stream>>>(xg, whh0, h0t, T_);
    // Layer 1 (transposed A)
    gemm_xg_tA<<<dim3(B_ * 21), dim3(256), 0, stream>>>(h0t, wih1, b1, xg, T_);
    lstm_scan<<<dim3(B_ * 2), dim3(64), 0, stream>>>(xg, whh1, h1t, T_);
    // FC (transposed input, coalesced)
    fc_t<<<dim3(B_, 2), dim3(256), 0, stream>>>(h1t, fcw, fcb, out, T_);
}